// Round 2
// baseline (637.445 us; speedup 1.0000x reference)
//
#include <hip/hip_runtime.h>
#include <cmath>

#define TT   6
#define NB   128
#define DIM  192
#define SCALE 0.17677669529663687f

typedef __attribute__((ext_vector_type(8))) short v8s;
typedef __attribute__((ext_vector_type(4))) float v4f;

__device__ __forceinline__ short f2bf(float f) {
  union { float f; unsigned u; } v; v.f = f;
  unsigned r = v.u + 0x7fffu + ((v.u >> 16) & 1u);
  return (short)(r >> 16);
}

// ---- fused prep: bf16 weight conversion + sine position table, one launch ----
__global__ void prep_kernel(const float* __restrict__ Wqkv, const float* __restrict__ Wproj,
                            const float* __restrict__ W1, const float* __restrict__ W2,
                            short* __restrict__ dWqkv, short* __restrict__ dWproj,
                            short* __restrict__ dW1, short* __restrict__ dW2,
                            float* __restrict__ pos) {
  int idx = blockIdx.x * 256 + threadIdx.x;
  const float* src = nullptr; short* dst = nullptr; int off = 0;
  if (idx < 27648)      { src = Wqkv;  dst = dWqkv;  off = idx; }
  else if (idx < 46080) { src = Wproj; dst = dWproj; off = idx - 27648; }
  else if (idx < 55296) { src = W1;    dst = dW1;    off = idx - 46080; }
  else if (idx < 64512) { src = W2;    dst = dW2;    off = idx - 55296; }
  else if (idx < 67584) {
    int p0 = (idx - 64512) * 4;
    float4 r;
    float* rp = (float*)&r;
#pragma unroll
    for (int jj = 0; jj < 4; jj++) {
      int p = p0 + jj;
      int row = p / 192, c = p - row * 192;
      int e  = (c < 96) ? (row >> 3) : (row & 7);
      int cc = (c < 96) ? c : c - 96;
      int m = cc >> 1;
      float embed = (float)(e + 1) * (6.283185307179586f / 8.000001f);
      float dt = powf(10000.0f, (float)m * (1.0f / 48.0f));
      float ang = embed / dt;
      rp[jj] = (cc & 1) ? cosf(ang) : sinf(ang);
    }
    *(float4*)(pos + p0) = r;
    return;
  } else return;
  const float* s = src + off * 4;
  short4 r;
  r.x = f2bf(s[0]); r.y = f2bf(s[1]); r.z = f2bf(s[2]); r.w = f2bf(s[3]);
  *(short4*)(dst + off * 4) = r;
}

// ---- QKV pre-kernel: one block per (b,t). Q,K row-major [hw][ch]; V transposed [ch][hw]. ----
__global__ __launch_bounds__(256) void qkv_kernel(
    const float* __restrict__ x, const float* __restrict__ pos,
    const short* __restrict__ Wqkv_bf,
    short* __restrict__ Qb, short* __restrict__ Kb, short* __restrict__ Vtb) {
  __shared__ short XP[64 * 200];
  int bid = blockIdx.x;
  int t = bid % TT, b = bid / TT;
  int tid = threadIdx.x, w = tid >> 6, lane = tid & 63;
  int l15 = lane & 15, quad = lane >> 4;
  const float* xrow = x + (size_t)(b * (TT * 64) + t * 64) * DIM;
  for (int c = tid; c < 64 * 24; c += 256) {
    int row = c / 24, col8 = (c - (c / 24) * 24) * 8;
    const float* xs = xrow + row * DIM + col8;
    const float* pp = pos + row * DIM + col8;
    v8s r8;
#pragma unroll
    for (int jj = 0; jj < 8; jj++) r8[jj] = f2bf(xs[jj] + pp[jj]);
    *(v8s*)(XP + row * 200 + col8) = r8;
  }
  __syncthreads();
  const v4f vzero = {0.f, 0.f, 0.f, 0.f};
  size_t obase = (size_t)(b * TT + t) * 64 * DIM;
#pragma unroll
  for (int cti = 0; cti < 9; cti++) {
    int r0 = w * 144 + cti * 16;
    v4f acc[4] = {vzero, vzero, vzero, vzero};
#pragma unroll
    for (int ks = 0; ks < 6; ks++) {
      v8s a = *(const v8s*)(Wqkv_bf + (size_t)(r0 + l15) * 192 + ks * 32 + quad * 8);
#pragma unroll
      for (int nt = 0; nt < 4; nt++) {
        v8s bb = *(const v8s*)(XP + (nt * 16 + l15) * 200 + ks * 32 + quad * 8);
        acc[nt] = __builtin_amdgcn_mfma_f32_16x16x32_bf16(a, bb, acc[nt], 0, 0, 0);
      }
    }
    int R = r0 + quad * 4;
#pragma unroll
    for (int nt = 0; nt < 4; nt++) {
      int hw = nt * 16 + l15;
      if (R < 192) {
        short4 s;
        s.x = f2bf(acc[nt][0] * SCALE); s.y = f2bf(acc[nt][1] * SCALE);
        s.z = f2bf(acc[nt][2] * SCALE); s.w = f2bf(acc[nt][3] * SCALE);
        *(short4*)(Qb + obase + (size_t)hw * 192 + R) = s;
      } else if (R < 384) {
        short4 s;
        s.x = f2bf(acc[nt][0]); s.y = f2bf(acc[nt][1]);
        s.z = f2bf(acc[nt][2]); s.w = f2bf(acc[nt][3]);
        *(short4*)(Kb + obase + (size_t)hw * 192 + (R - 192)) = s;
      } else {
#pragma unroll
        for (int r = 0; r < 4; r++)
          Vtb[obase + (size_t)(R - 384 + r) * 64 + hw] = f2bf(acc[nt][r]);
      }
    }
  }
}

// ---- main fused kernel: one block per (i,b), 512 threads (8 waves).
// GEMM split: wave (wc=w&3, wh=w>>2): 48-ch slice x 32-hw half.
// Attention: wave (qt=wc, hg=wh): 16 q-rows x 3 heads. P redistributed in-register
// (cvt_pk_bf16 + ds_bpermute quad-transpose) -> no Pl LDS, no lgkmcnt(0) fences.
// Xi resident in LDS; xi-half of G1 recomputed per j (bit-identical, MFMA pipe is idle).
// LDS 53248 -> 3 blocks/CU; persistent regs = acc(24)+qa(12) -> target 6 waves/EU.
__global__ __launch_bounds__(512, 6) void fused_all(
    const float* __restrict__ x,
    const short* __restrict__ Qb, const short* __restrict__ Kb,
    const short* __restrict__ Vtb,
    const short* __restrict__ Wproj_bf, const short* __restrict__ W1_bf,
    const short* __restrict__ W2_bf,
    const float* __restrict__ bproj, const float* __restrict__ gamma,
    const float* __restrict__ beta, const float* __restrict__ b1,
    const float* __restrict__ b2,
    float* __restrict__ out) {
  __shared__ short SP[64 * 200];     // o / y1n / h: [hw][ch]
  __shared__ short XI[64 * 200];     // bf16 x-view rows, resident all j
  __shared__ float LNp[64][4][2];    // LN partials: [hw][wc][s1,s2]

  // XCD swizzle: 6 i-blocks sharing b land on one XCD (shared Q/K/V in its L2)
  int bid = blockIdx.x;
  int xcd = bid & 7, idx6 = bid >> 3;
  int bq = idx6 / TT;
  int b = xcd * 16 + bq, i = idx6 - bq * TT;

  int tid = threadIdx.x, w = tid >> 6, lane = tid & 63;
  int l15 = lane & 15, quad = lane >> 4;
  int wc = w & 3, wh = w >> 2;
  int cb = wc * 48;
  const v4f vzero = {0.f, 0.f, 0.f, 0.f};

  // ---- stage Xi (x.view reinterpretation rows) as bf16, resident ----
  const float* xi = x + (size_t)(i * NB + b) * 64 * DIM;
  for (int c = tid; c < 64 * 24; c += 512) {
    int row = c / 24, col8 = (c - (c / 24) * 24) * 8;
    const float* xs = xi + row * DIM + col8;
    v8s r8;
#pragma unroll
    for (int jj = 0; jj < 8; jj++) r8[jj] = f2bf(xs[jj]);
    *(v8s*)(XI + row * 200 + col8) = r8;
  }

  // ---- hoist Q fragments (j-invariant): wave's 16 q-rows x its 3 heads ----
  const short* Qi = Qb + (size_t)(b * TT + i) * 64 * DIM;
  v8s qa[3];
#pragma unroll
  for (int hh = 0; hh < 3; hh++)
    qa[hh] = *(const v8s*)(Qi + (size_t)(wc * 16 + l15) * 192 + (wh * 3 + hh) * 32 + quad * 8);

  v4f acc[3][2];
#pragma unroll
  for (int cti = 0; cti < 3; cti++)
#pragma unroll
    for (int nt = 0; nt < 2; nt++) acc[cti][nt] = vzero;

  __syncthreads();                   // XI staged

  int srcA = l15 + ((lane & 16) << 1);   // l15 + 32*(quad&1)
  int srcB = srcA + 16;
  bool hiq = (lane & 32) != 0;           // quad >= 2

  for (int j = 0; j < TT; j++) {
    __syncthreads();               // prior SP reads (G3 h) done before o overwrites
    const short* Kj = Kb + (size_t)(b * TT + j) * 64 * DIM;
    const short* Vj = Vtb + (size_t)(b * TT + j) * 64 * DIM;

    // ---- attention ----
#pragma unroll
    for (int hh = 0; hh < 3; hh++) {
      int h = wh * 3 + hh;
      v4f S[4];
#pragma unroll
      for (int cta = 0; cta < 4; cta++) {
        v8s akq = *(const v8s*)(Kj + (size_t)(cta * 16 + l15) * 192 + h * 32 + quad * 8);
        S[cta] = __builtin_amdgcn_mfma_f32_16x16x32_bf16(akq, qa[hh], vzero, 0, 0, 0);
      }
      // softmax over k (per lane: q=l15, k=cta*16+quad*4+r)
      float mx = -1e30f;
#pragma unroll
      for (int cta = 0; cta < 4; cta++)
#pragma unroll
        for (int r = 0; r < 4; r++) mx = fmaxf(mx, S[cta][r]);
      mx = fmaxf(mx, __shfl_xor(mx, 16, 64));
      mx = fmaxf(mx, __shfl_xor(mx, 32, 64));
      float sum = 0.f;
#pragma unroll
      for (int cta = 0; cta < 4; cta++)
#pragma unroll
        for (int r = 0; r < 4; r++) {
          float e = __expf(S[cta][r] - mx);
          S[cta][r] = e; sum += e;
        }
      sum += __shfl_xor(sum, 16, 64);
      sum += __shfl_xor(sum, 32, 64);
      float inv = 1.0f / sum;
      // pack P to bf16 pairs: pk[cta][w] = {P[4cta..]*inv}
      unsigned pk[4][2];
#pragma unroll
      for (int cta = 0; cta < 4; cta++) {
        float a0 = S[cta][0] * inv, a1 = S[cta][1] * inv;
        float a2 = S[cta][2] * inv, a3 = S[cta][3] * inv;
        __asm__("v_cvt_pk_bf16_f32 %0, %1, %2" : "=v"(pk[cta][0]) : "v"(a0), "v"(a1));
        __asm__("v_cvt_pk_bf16_f32 %0, %1, %2" : "=v"(pk[cta][1]) : "v"(a2), "v"(a3));
      }
      // quad-transpose: target lane(l15,quad) word layout k = quad*8+e (bp0), +32 (bp1)
      unsigned t00 = (unsigned)__shfl((int)pk[0][0], srcA), t10 = (unsigned)__shfl((int)pk[1][0], srcA);
      unsigned t01 = (unsigned)__shfl((int)pk[0][1], srcA), t11 = (unsigned)__shfl((int)pk[1][1], srcA);
      unsigned u00 = (unsigned)__shfl((int)pk[0][0], srcB), u10 = (unsigned)__shfl((int)pk[1][0], srcB);
      unsigned u01 = (unsigned)__shfl((int)pk[0][1], srcB), u11 = (unsigned)__shfl((int)pk[1][1], srcB);
      unsigned s20 = (unsigned)__shfl((int)pk[2][0], srcA), s30 = (unsigned)__shfl((int)pk[3][0], srcA);
      unsigned s21 = (unsigned)__shfl((int)pk[2][1], srcA), s31 = (unsigned)__shfl((int)pk[3][1], srcA);
      unsigned v20 = (unsigned)__shfl((int)pk[2][0], srcB), v30 = (unsigned)__shfl((int)pk[3][0], srcB);
      unsigned v21 = (unsigned)__shfl((int)pk[2][1], srcB), v31 = (unsigned)__shfl((int)pk[3][1], srcB);
      union { unsigned u[4]; v8s v; } B0, B1;
      B0.u[0] = hiq ? t10 : t00;  B0.u[1] = hiq ? t11 : t01;
      B0.u[2] = hiq ? u10 : u00;  B0.u[3] = hiq ? u11 : u01;
      B1.u[0] = hiq ? s30 : s20;  B1.u[1] = hiq ? s31 : s21;
      B1.u[2] = hiq ? v30 : v20;  B1.u[3] = hiq ? v31 : v21;
      // PV
#pragma unroll
      for (int ct2 = 0; ct2 < 2; ct2++) {
        v8s av0 = *(const v8s*)(Vj + (size_t)(h * 32 + ct2 * 16 + l15) * 64 + quad * 8);
        v8s av1 = *(const v8s*)(Vj + (size_t)(h * 32 + ct2 * 16 + l15) * 64 + 32 + quad * 8);
        v4f o = __builtin_amdgcn_mfma_f32_16x16x32_bf16(av0, B0.v, vzero, 0, 0, 0);
        o = __builtin_amdgcn_mfma_f32_16x16x32_bf16(av1, B1.v, o, 0, 0, 0);
        short4 s;
        s.x = f2bf(o[0]); s.y = f2bf(o[1]); s.z = f2bf(o[2]); s.w = f2bf(o[3]);
        *(short4*)(&SP[(wc * 16 + l15) * 200 + h * 32 + ct2 * 16 + quad * 4]) = s;
      }
    }
    __syncthreads();               // o complete

    // ---- G1: y1 = Wproj[:,0:192] . o^T + Wproj[:,192:384] . Xi^T ----
    v4f y1[3][2];
#pragma unroll
    for (int cti = 0; cti < 3; cti++)
#pragma unroll
      for (int nt = 0; nt < 2; nt++) y1[cti][nt] = vzero;
#pragma unroll
    for (int ks = 0; ks < 6; ks++) {
      v8s bo[2];
#pragma unroll
      for (int nt = 0; nt < 2; nt++)
        bo[nt] = *(const v8s*)(SP + (wh * 32 + nt * 16 + l15) * 200 + ks * 32 + quad * 8);
#pragma unroll
      for (int cti = 0; cti < 3; cti++) {
        v8s a = *(const v8s*)(Wproj_bf + (size_t)(cb + cti * 16 + l15) * 384 + ks * 32 + quad * 8);
#pragma unroll
        for (int nt = 0; nt < 2; nt++)
          y1[cti][nt] = __builtin_amdgcn_mfma_f32_16x16x32_bf16(a, bo[nt], y1[cti][nt], 0, 0, 0);
      }
    }
#pragma unroll
    for (int ks = 0; ks < 6; ks++) {
      v8s bxi[2];
#pragma unroll
      for (int nt = 0; nt < 2; nt++)
        bxi[nt] = *(const v8s*)(XI + (wh * 32 + nt * 16 + l15) * 200 + ks * 32 + quad * 8);
#pragma unroll
      for (int cti = 0; cti < 3; cti++) {
        v8s a = *(const v8s*)(Wproj_bf + (size_t)(cb + cti * 16 + l15) * 384 + 192 + ks * 32 + quad * 8);
#pragma unroll
        for (int nt = 0; nt < 2; nt++)
          y1[cti][nt] = __builtin_amdgcn_mfma_f32_16x16x32_bf16(a, bxi[nt], y1[cti][nt], 0, 0, 0);
      }
    }
    // + bproj; LN partials
#pragma unroll
    for (int cti = 0; cti < 3; cti++) {
      float4 bp4 = *(const float4*)(bproj + cb + cti * 16 + quad * 4);
#pragma unroll
      for (int nt = 0; nt < 2; nt++) {
        y1[cti][nt][0] += bp4.x; y1[cti][nt][1] += bp4.y;
        y1[cti][nt][2] += bp4.z; y1[cti][nt][3] += bp4.w;
      }
    }
#pragma unroll
    for (int nt = 0; nt < 2; nt++) {
      float s1 = 0.f, s2 = 0.f;
#pragma unroll
      for (int cti = 0; cti < 3; cti++)
#pragma unroll
        for (int r = 0; r < 4; r++) { float v = y1[cti][nt][r]; s1 += v; s2 += v * v; }
      s1 += __shfl_xor(s1, 16, 64); s2 += __shfl_xor(s2, 16, 64);
      s1 += __shfl_xor(s1, 32, 64); s2 += __shfl_xor(s2, 32, 64);
      if (quad == 0) {
        LNp[wh * 32 + nt * 16 + l15][wc][0] = s1;
        LNp[wh * 32 + nt * 16 + l15][wc][1] = s2;
      }
    }
    __syncthreads();               // partials visible; G1 strip reads done
    float mu[2], rs[2];
#pragma unroll
    for (int nt = 0; nt < 2; nt++) {
      int row = wh * 32 + nt * 16 + l15;
      float s1 = 0.f, s2 = 0.f;
#pragma unroll
      for (int ww = 0; ww < 4; ww++) { s1 += LNp[row][ww][0]; s2 += LNp[row][ww][1]; }
      float m = s1 * (1.0f / 192.0f);
      mu[nt] = m; rs[nt] = rsqrtf(s2 * (1.0f / 192.0f) - m * m + 1e-5f);
    }
#pragma unroll
    for (int cti = 0; cti < 3; cti++) {
      float4 g4 = *(const float4*)(gamma + cb + cti * 16 + quad * 4);
      float4 be4 = *(const float4*)(beta + cb + cti * 16 + quad * 4);
#pragma unroll
      for (int nt = 0; nt < 2; nt++) {
        short4 s;
        s.x = f2bf((y1[cti][nt][0] - mu[nt]) * rs[nt] * g4.x + be4.x);
        s.y = f2bf((y1[cti][nt][1] - mu[nt]) * rs[nt] * g4.y + be4.y);
        s.z = f2bf((y1[cti][nt][2] - mu[nt]) * rs[nt] * g4.z + be4.z);
        s.w = f2bf((y1[cti][nt][3] - mu[nt]) * rs[nt] * g4.w + be4.w);
        *(short4*)(&SP[(wh * 32 + nt * 16 + l15) * 200 + cb + cti * 16 + quad * 4]) = s;
      }
    }
    __syncthreads();               // y1n ready

    // ---- G2: y2 = W1 . y1n^T ----
    v4f y2[3][2];
#pragma unroll
    for (int cti = 0; cti < 3; cti++)
#pragma unroll
      for (int nt = 0; nt < 2; nt++) y2[cti][nt] = vzero;
#pragma unroll
    for (int ks = 0; ks < 6; ks++) {
      v8s bh[2];
#pragma unroll
      for (int nt = 0; nt < 2; nt++)
        bh[nt] = *(const v8s*)(SP + (wh * 32 + nt * 16 + l15) * 200 + ks * 32 + quad * 8);
#pragma unroll
      for (int cti = 0; cti < 3; cti++) {
        v8s a = *(const v8s*)(W1_bf + (size_t)(cb + cti * 16 + l15) * 192 + ks * 32 + quad * 8);
#pragma unroll
        for (int nt = 0; nt < 2; nt++)
          y2[cti][nt] = __builtin_amdgcn_mfma_f32_16x16x32_bf16(a, bh[nt], y2[cti][nt], 0, 0, 0);
      }
    }
    __syncthreads();               // G2 strip reads done before h overwrite
#pragma unroll
    for (int cti = 0; cti < 3; cti++) {
      float4 b14 = *(const float4*)(b1 + cb + cti * 16 + quad * 4);
#pragma unroll
      for (int nt = 0; nt < 2; nt++) {
        float vv[4] = {y2[cti][nt][0] + b14.x, y2[cti][nt][1] + b14.y,
                       y2[cti][nt][2] + b14.z, y2[cti][nt][3] + b14.w};
        short sv[4];
#pragma unroll
        for (int r = 0; r < 4; r++) {
          float v = vv[r];
          float t = 0.79788456080286536f * (v + 0.044715f * v * v * v);
          float e = __expf(2.0f * t);
          float th = 1.0f - 2.0f / (e + 1.0f);
          sv[r] = f2bf(0.5f * v * (1.0f + th));
        }
        short4 s;
        s.x = sv[0]; s.y = sv[1]; s.z = sv[2]; s.w = sv[3];
        *(short4*)(&SP[(wh * 32 + nt * 16 + l15) * 200 + cb + cti * 16 + quad * 4]) = s;
      }
    }
    __syncthreads();               // h ready

    // ---- G3: acc += W2 . h^T ----
#pragma unroll
    for (int ks = 0; ks < 6; ks++) {
      v8s bh[2];
#pragma unroll
      for (int nt = 0; nt < 2; nt++)
        bh[nt] = *(const v8s*)(SP + (wh * 32 + nt * 16 + l15) * 200 + ks * 32 + quad * 8);
#pragma unroll
      for (int cti = 0; cti < 3; cti++) {
        v8s a = *(const v8s*)(W2_bf + (size_t)(cb + cti * 16 + l15) * 192 + ks * 32 + quad * 8);
#pragma unroll
        for (int nt = 0; nt < 2; nt++)
          acc[cti][nt] = __builtin_amdgcn_mfma_f32_16x16x32_bf16(a, bh[nt], acc[cti][nt], 0, 0, 0);
      }
    }
  }

  // ---- epilogue: out = [x | x + acc/6 + b2] ----
#pragma unroll
  for (int cti = 0; cti < 3; cti++) {
    int cc0 = cb + cti * 16 + quad * 4;
    float4 b24 = *(const float4*)(b2 + cc0);
#pragma unroll
    for (int nt = 0; nt < 2; nt++) {
      int hw = wh * 32 + nt * 16 + l15;
      size_t nrow = (size_t)b * 384 + (size_t)i * 64 + hw;
      float4 xv = *(const float4*)(x + nrow * DIM + cc0);
      float4 o4;
      o4.x = xv.x + acc[cti][nt][0] * (1.0f / 6.0f) + b24.x;
      o4.y = xv.y + acc[cti][nt][1] * (1.0f / 6.0f) + b24.y;
      o4.z = xv.z + acc[cti][nt][2] * (1.0f / 6.0f) + b24.z;
      o4.w = xv.w + acc[cti][nt][3] * (1.0f / 6.0f) + b24.w;
      *(float4*)(out + nrow * 384 + 192 + cc0) = o4;
    }
  }
  // x-half bit-exact copy
  for (int c = tid; c < 64 * 48; c += 512) {
    int row = c / 48, col4 = (c - (c / 48) * 48) * 4;
    size_t nrow = (size_t)b * 384 + (size_t)i * 64 + row;
    *(float4*)(out + nrow * 384 + col4) = *(const float4*)(x + nrow * DIM + col4);
  }
}

extern "C" void kernel_launch(void* const* d_in, const int* in_sizes, int n_in,
                              void* d_out, int out_size, void* d_ws, size_t ws_size,
                              hipStream_t stream) {
  (void)in_sizes; (void)n_in; (void)out_size; (void)ws_size;
  const float* x     = (const float*)d_in[0];
  const float* Wqkv  = (const float*)d_in[1];
  const float* Wproj = (const float*)d_in[2];
  const float* bproj = (const float*)d_in[3];
  const float* gamma = (const float*)d_in[4];
  const float* beta  = (const float*)d_in[5];
  const float* W1    = (const float*)d_in[6];
  const float* b1    = (const float*)d_in[7];
  const float* W2    = (const float*)d_in[8];
  const float* b2    = (const float*)d_in[9];
  float* out = (float*)d_out;

  // workspace: weights bf16 + pos f32 + Q/K/Vt bf16
  short* Wqkv_bf  = (short*)d_ws;                 // 576*192
  short* Wproj_bf = Wqkv_bf + 110592;             // 192*384
  short* W1_bf    = Wproj_bf + 73728;             // 192*192
  short* W2_bf    = W1_bf + 36864;                // 192*192
  float* pos_f    = (float*)(W2_bf + 36864);      // 64*192 f32
  short* Qb       = (short*)(pos_f + 12288);      // [b][t][hw][ch]
  short* Kb       = Qb + 9437184;                 // [b][t][hw][ch]
  short* Vtb      = Kb + 9437184;                 // [b][t][ch][hw]

  prep_kernel<<<dim3(264), dim3(256), 0, stream>>>(
      Wqkv, Wproj, W1, W2, Wqkv_bf, Wproj_bf, W1_bf, W2_bf, pos_f);
  qkv_kernel<<<dim3(TT * NB), dim3(256), 0, stream>>>(x, pos_f, Wqkv_bf, Qb, Kb, Vtb);
  fused_all<<<dim3(TT * NB), dim3(512), 0, stream>>>(
      x, Qb, Kb, Vtb, Wproj_bf, W1_bf, W2_bf, bproj, gamma, beta, b1, b2, out);
}

// Round 3
// 632.634 us; speedup vs baseline: 1.0076x; 1.0076x over previous
//
#include <hip/hip_runtime.h>
#include <cmath>

#define TT   6
#define NB   128
#define DIM  192
#define SCALE 0.17677669529663687f

typedef __attribute__((ext_vector_type(8))) short v8s;
typedef __attribute__((ext_vector_type(4))) float v4f;

__device__ __forceinline__ short f2bf(float f) {
  union { float f; unsigned u; } v; v.f = f;
  unsigned r = v.u + 0x7fffu + ((v.u >> 16) & 1u);
  return (short)(r >> 16);
}

// ---- fused prep: bf16 weight conversion + sine position table, one launch ----
__global__ void prep_kernel(const float* __restrict__ Wqkv, const float* __restrict__ Wproj,
                            const float* __restrict__ W1, const float* __restrict__ W2,
                            short* __restrict__ dWqkv, short* __restrict__ dWproj,
                            short* __restrict__ dW1, short* __restrict__ dW2,
                            float* __restrict__ pos) {
  int idx = blockIdx.x * 256 + threadIdx.x;
  const float* src = nullptr; short* dst = nullptr; int off = 0;
  if (idx < 27648)      { src = Wqkv;  dst = dWqkv;  off = idx; }
  else if (idx < 46080) { src = Wproj; dst = dWproj; off = idx - 27648; }
  else if (idx < 55296) { src = W1;    dst = dW1;    off = idx - 46080; }
  else if (idx < 64512) { src = W2;    dst = dW2;    off = idx - 55296; }
  else if (idx < 67584) {
    int p0 = (idx - 64512) * 4;
    float4 r;
    float* rp = (float*)&r;
#pragma unroll
    for (int jj = 0; jj < 4; jj++) {
      int p = p0 + jj;
      int row = p / 192, c = p - row * 192;
      int e  = (c < 96) ? (row >> 3) : (row & 7);
      int cc = (c < 96) ? c : c - 96;
      int m = cc >> 1;
      float embed = (float)(e + 1) * (6.283185307179586f / 8.000001f);
      float dt = powf(10000.0f, (float)m * (1.0f / 48.0f));
      float ang = embed / dt;
      rp[jj] = (cc & 1) ? cosf(ang) : sinf(ang);
    }
    *(float4*)(pos + p0) = r;
    return;
  } else return;
  const float* s = src + off * 4;
  short4 r;
  r.x = f2bf(s[0]); r.y = f2bf(s[1]); r.z = f2bf(s[2]); r.w = f2bf(s[3]);
  *(short4*)(dst + off * 4) = r;
}

// ---- QKV pre-kernel: one block per (b,t). Q,K row-major [hw][ch]; V transposed [ch][hw].
// Grid swizzled with the SAME XCD mapping as fused_all (b in [xcd*16, xcd*16+16)),
// so Q/K/V are produced into the same per-XCD L2 that consumes them.
__global__ __launch_bounds__(256) void qkv_kernel(
    const float* __restrict__ x, const float* __restrict__ pos,
    const short* __restrict__ Wqkv_bf,
    short* __restrict__ Qb, short* __restrict__ Kb, short* __restrict__ Vtb) {
  __shared__ short XP[64 * 200];
  int bid = blockIdx.x;
  int xcd = bid & 7, idx = bid >> 3;   // 96 blocks per XCD
  int bq = idx / TT;
  int b = xcd * 16 + bq, t = idx - bq * TT;
  int tid = threadIdx.x, w = tid >> 6, lane = tid & 63;
  int l15 = lane & 15, quad = lane >> 4;
  const float* xrow = x + (size_t)(b * (TT * 64) + t * 64) * DIM;
  for (int c = tid; c < 64 * 24; c += 256) {
    int row = c / 24, col8 = (c - (c / 24) * 24) * 8;
    const float* xs = xrow + row * DIM + col8;
    const float* pp = pos + row * DIM + col8;
    v8s r8;
#pragma unroll
    for (int jj = 0; jj < 8; jj++) r8[jj] = f2bf(xs[jj] + pp[jj]);
    *(v8s*)(XP + row * 200 + col8) = r8;
  }
  __syncthreads();
  const v4f vzero = {0.f, 0.f, 0.f, 0.f};
  size_t obase = (size_t)(b * TT + t) * 64 * DIM;
#pragma unroll
  for (int cti = 0; cti < 9; cti++) {
    int r0 = w * 144 + cti * 16;
    v4f acc[4] = {vzero, vzero, vzero, vzero};
#pragma unroll
    for (int ks = 0; ks < 6; ks++) {
      v8s a = *(const v8s*)(Wqkv_bf + (size_t)(r0 + l15) * 192 + ks * 32 + quad * 8);
#pragma unroll
      for (int nt = 0; nt < 4; nt++) {
        v8s bb = *(const v8s*)(XP + (nt * 16 + l15) * 200 + ks * 32 + quad * 8);
        acc[nt] = __builtin_amdgcn_mfma_f32_16x16x32_bf16(a, bb, acc[nt], 0, 0, 0);
      }
    }
    int R = r0 + quad * 4;
#pragma unroll
    for (int nt = 0; nt < 4; nt++) {
      int hw = nt * 16 + l15;
      if (R < 192) {
        short4 s;
        s.x = f2bf(acc[nt][0] * SCALE); s.y = f2bf(acc[nt][1] * SCALE);
        s.z = f2bf(acc[nt][2] * SCALE); s.w = f2bf(acc[nt][3] * SCALE);
        *(short4*)(Qb + obase + (size_t)hw * 192 + R) = s;
      } else if (R < 384) {
        short4 s;
        s.x = f2bf(acc[nt][0]); s.y = f2bf(acc[nt][1]);
        s.z = f2bf(acc[nt][2]); s.w = f2bf(acc[nt][3]);
        *(short4*)(Kb + obase + (size_t)hw * 192 + (R - 192)) = s;
      } else {
#pragma unroll
        for (int r = 0; r < 4; r++)
          Vtb[obase + (size_t)(R - 384 + r) * 64 + hw] = f2bf(acc[nt][r]);
      }
    }
  }
}

// ---- main fused kernel: one block per (i,b), 512 threads (8 waves).
// Structure identical to round 2 except the epilogue: acc staged to LDS (f32)
// and written as full contiguous 768B row segments (no partial-line RMW),
// with the x-copy fused into the same loop (x read once).
__global__ __launch_bounds__(512, 6) void fused_all(
    const float* __restrict__ x,
    const short* __restrict__ Qb, const short* __restrict__ Kb,
    const short* __restrict__ Vtb,
    const short* __restrict__ Wproj_bf, const short* __restrict__ W1_bf,
    const short* __restrict__ W2_bf,
    const float* __restrict__ bproj, const float* __restrict__ gamma,
    const float* __restrict__ beta, const float* __restrict__ b1,
    const float* __restrict__ b2,
    float* __restrict__ out) {
  __shared__ short SP[64 * 200];     // o / y1n / h: [hw][ch]; f32 acc staging in epilogue
  __shared__ short XI[64 * 200];     // bf16 x-view rows, resident all j
  __shared__ float LNp[64][4][2];    // LN partials: [hw][wc][s1,s2]

  // XCD swizzle: 6 i-blocks sharing b land on one XCD (shared Q/K/V in its L2)
  int bid = blockIdx.x;
  int xcd = bid & 7, idx6 = bid >> 3;
  int bq = idx6 / TT;
  int b = xcd * 16 + bq, i = idx6 - bq * TT;

  int tid = threadIdx.x, w = tid >> 6, lane = tid & 63;
  int l15 = lane & 15, quad = lane >> 4;
  int wc = w & 3, wh = w >> 2;
  int cb = wc * 48;
  const v4f vzero = {0.f, 0.f, 0.f, 0.f};

  // ---- stage Xi (x.view reinterpretation rows) as bf16, resident ----
  const float* xi = x + (size_t)(i * NB + b) * 64 * DIM;
  for (int c = tid; c < 64 * 24; c += 512) {
    int row = c / 24, col8 = (c - (c / 24) * 24) * 8;
    const float* xs = xi + row * DIM + col8;
    v8s r8;
#pragma unroll
    for (int jj = 0; jj < 8; jj++) r8[jj] = f2bf(xs[jj]);
    *(v8s*)(XI + row * 200 + col8) = r8;
  }

  // ---- hoist Q fragments (j-invariant): wave's 16 q-rows x its 3 heads ----
  const short* Qi = Qb + (size_t)(b * TT + i) * 64 * DIM;
  v8s qa[3];
#pragma unroll
  for (int hh = 0; hh < 3; hh++)
    qa[hh] = *(const v8s*)(Qi + (size_t)(wc * 16 + l15) * 192 + (wh * 3 + hh) * 32 + quad * 8);

  v4f acc[3][2];
#pragma unroll
  for (int cti = 0; cti < 3; cti++)
#pragma unroll
    for (int nt = 0; nt < 2; nt++) acc[cti][nt] = vzero;

  __syncthreads();                   // XI staged

  int srcA = l15 + ((lane & 16) << 1);   // l15 + 32*(quad&1)
  int srcB = srcA + 16;
  bool hiq = (lane & 32) != 0;           // quad >= 2

  for (int j = 0; j < TT; j++) {
    __syncthreads();               // prior SP reads (G3 h) done before o overwrites
    const short* Kj = Kb + (size_t)(b * TT + j) * 64 * DIM;
    const short* Vj = Vtb + (size_t)(b * TT + j) * 64 * DIM;

    // ---- attention ----
#pragma unroll
    for (int hh = 0; hh < 3; hh++) {
      int h = wh * 3 + hh;
      v4f S[4];
#pragma unroll
      for (int cta = 0; cta < 4; cta++) {
        v8s akq = *(const v8s*)(Kj + (size_t)(cta * 16 + l15) * 192 + h * 32 + quad * 8);
        S[cta] = __builtin_amdgcn_mfma_f32_16x16x32_bf16(akq, qa[hh], vzero, 0, 0, 0);
      }
      // softmax over k (per lane: q=l15, k=cta*16+quad*4+r)
      float mx = -1e30f;
#pragma unroll
      for (int cta = 0; cta < 4; cta++)
#pragma unroll
        for (int r = 0; r < 4; r++) mx = fmaxf(mx, S[cta][r]);
      mx = fmaxf(mx, __shfl_xor(mx, 16, 64));
      mx = fmaxf(mx, __shfl_xor(mx, 32, 64));
      float sum = 0.f;
#pragma unroll
      for (int cta = 0; cta < 4; cta++)
#pragma unroll
        for (int r = 0; r < 4; r++) {
          float e = __expf(S[cta][r] - mx);
          S[cta][r] = e; sum += e;
        }
      sum += __shfl_xor(sum, 16, 64);
      sum += __shfl_xor(sum, 32, 64);
      float inv = 1.0f / sum;
      // pack P to bf16 pairs
      unsigned pk[4][2];
#pragma unroll
      for (int cta = 0; cta < 4; cta++) {
        float a0 = S[cta][0] * inv, a1 = S[cta][1] * inv;
        float a2 = S[cta][2] * inv, a3 = S[cta][3] * inv;
        __asm__("v_cvt_pk_bf16_f32 %0, %1, %2" : "=v"(pk[cta][0]) : "v"(a0), "v"(a1));
        __asm__("v_cvt_pk_bf16_f32 %0, %1, %2" : "=v"(pk[cta][1]) : "v"(a2), "v"(a3));
      }
      // quad-transpose to PV B-fragment layout
      unsigned t00 = (unsigned)__shfl((int)pk[0][0], srcA), t10 = (unsigned)__shfl((int)pk[1][0], srcA);
      unsigned t01 = (unsigned)__shfl((int)pk[0][1], srcA), t11 = (unsigned)__shfl((int)pk[1][1], srcA);
      unsigned u00 = (unsigned)__shfl((int)pk[0][0], srcB), u10 = (unsigned)__shfl((int)pk[1][0], srcB);
      unsigned u01 = (unsigned)__shfl((int)pk[0][1], srcB), u11 = (unsigned)__shfl((int)pk[1][1], srcB);
      unsigned s20 = (unsigned)__shfl((int)pk[2][0], srcA), s30 = (unsigned)__shfl((int)pk[3][0], srcA);
      unsigned s21 = (unsigned)__shfl((int)pk[2][1], srcA), s31 = (unsigned)__shfl((int)pk[3][1], srcA);
      unsigned v20 = (unsigned)__shfl((int)pk[2][0], srcB), v30 = (unsigned)__shfl((int)pk[3][0], srcB);
      unsigned v21 = (unsigned)__shfl((int)pk[2][1], srcB), v31 = (unsigned)__shfl((int)pk[3][1], srcB);
      union { unsigned u[4]; v8s v; } B0, B1;
      B0.u[0] = hiq ? t10 : t00;  B0.u[1] = hiq ? t11 : t01;
      B0.u[2] = hiq ? u10 : u00;  B0.u[3] = hiq ? u11 : u01;
      B1.u[0] = hiq ? s30 : s20;  B1.u[1] = hiq ? s31 : s21;
      B1.u[2] = hiq ? v30 : v20;  B1.u[3] = hiq ? v31 : v21;
      // PV
#pragma unroll
      for (int ct2 = 0; ct2 < 2; ct2++) {
        v8s av0 = *(const v8s*)(Vj + (size_t)(h * 32 + ct2 * 16 + l15) * 64 + quad * 8);
        v8s av1 = *(const v8s*)(Vj + (size_t)(h * 32 + ct2 * 16 + l15) * 64 + 32 + quad * 8);
        v4f o = __builtin_amdgcn_mfma_f32_16x16x32_bf16(av0, B0.v, vzero, 0, 0, 0);
        o = __builtin_amdgcn_mfma_f32_16x16x32_bf16(av1, B1.v, o, 0, 0, 0);
        short4 s;
        s.x = f2bf(o[0]); s.y = f2bf(o[1]); s.z = f2bf(o[2]); s.w = f2bf(o[3]);
        *(short4*)(&SP[(wc * 16 + l15) * 200 + h * 32 + ct2 * 16 + quad * 4]) = s;
      }
    }
    __syncthreads();               // o complete

    // ---- G1: y1 = Wproj[:,0:192] . o^T + Wproj[:,192:384] . Xi^T ----
    v4f y1[3][2];
#pragma unroll
    for (int cti = 0; cti < 3; cti++)
#pragma unroll
      for (int nt = 0; nt < 2; nt++) y1[cti][nt] = vzero;
#pragma unroll
    for (int ks = 0; ks < 6; ks++) {
      v8s bo[2];
#pragma unroll
      for (int nt = 0; nt < 2; nt++)
        bo[nt] = *(const v8s*)(SP + (wh * 32 + nt * 16 + l15) * 200 + ks * 32 + quad * 8);
#pragma unroll
      for (int cti = 0; cti < 3; cti++) {
        v8s a = *(const v8s*)(Wproj_bf + (size_t)(cb + cti * 16 + l15) * 384 + ks * 32 + quad * 8);
#pragma unroll
        for (int nt = 0; nt < 2; nt++)
          y1[cti][nt] = __builtin_amdgcn_mfma_f32_16x16x32_bf16(a, bo[nt], y1[cti][nt], 0, 0, 0);
      }
    }
#pragma unroll
    for (int ks = 0; ks < 6; ks++) {
      v8s bxi[2];
#pragma unroll
      for (int nt = 0; nt < 2; nt++)
        bxi[nt] = *(const v8s*)(XI + (wh * 32 + nt * 16 + l15) * 200 + ks * 32 + quad * 8);
#pragma unroll
      for (int cti = 0; cti < 3; cti++) {
        v8s a = *(const v8s*)(Wproj_bf + (size_t)(cb + cti * 16 + l15) * 384 + 192 + ks * 32 + quad * 8);
#pragma unroll
        for (int nt = 0; nt < 2; nt++)
          y1[cti][nt] = __builtin_amdgcn_mfma_f32_16x16x32_bf16(a, bxi[nt], y1[cti][nt], 0, 0, 0);
      }
    }
    // + bproj; LN partials
#pragma unroll
    for (int cti = 0; cti < 3; cti++) {
      float4 bp4 = *(const float4*)(bproj + cb + cti * 16 + quad * 4);
#pragma unroll
      for (int nt = 0; nt < 2; nt++) {
        y1[cti][nt][0] += bp4.x; y1[cti][nt][1] += bp4.y;
        y1[cti][nt][2] += bp4.z; y1[cti][nt][3] += bp4.w;
      }
    }
#pragma unroll
    for (int nt = 0; nt < 2; nt++) {
      float s1 = 0.f, s2 = 0.f;
#pragma unroll
      for (int cti = 0; cti < 3; cti++)
#pragma unroll
        for (int r = 0; r < 4; r++) { float v = y1[cti][nt][r]; s1 += v; s2 += v * v; }
      s1 += __shfl_xor(s1, 16, 64); s2 += __shfl_xor(s2, 16, 64);
      s1 += __shfl_xor(s1, 32, 64); s2 += __shfl_xor(s2, 32, 64);
      if (quad == 0) {
        LNp[wh * 32 + nt * 16 + l15][wc][0] = s1;
        LNp[wh * 32 + nt * 16 + l15][wc][1] = s2;
      }
    }
    __syncthreads();               // partials visible; G1 strip reads done
    float mu[2], rs[2];
#pragma unroll
    for (int nt = 0; nt < 2; nt++) {
      int row = wh * 32 + nt * 16 + l15;
      float s1 = 0.f, s2 = 0.f;
#pragma unroll
      for (int ww = 0; ww < 4; ww++) { s1 += LNp[row][ww][0]; s2 += LNp[row][ww][1]; }
      float m = s1 * (1.0f / 192.0f);
      mu[nt] = m; rs[nt] = rsqrtf(s2 * (1.0f / 192.0f) - m * m + 1e-5f);
    }
#pragma unroll
    for (int cti = 0; cti < 3; cti++) {
      float4 g4 = *(const float4*)(gamma + cb + cti * 16 + quad * 4);
      float4 be4 = *(const float4*)(beta + cb + cti * 16 + quad * 4);
#pragma unroll
      for (int nt = 0; nt < 2; nt++) {
        short4 s;
        s.x = f2bf((y1[cti][nt][0] - mu[nt]) * rs[nt] * g4.x + be4.x);
        s.y = f2bf((y1[cti][nt][1] - mu[nt]) * rs[nt] * g4.y + be4.y);
        s.z = f2bf((y1[cti][nt][2] - mu[nt]) * rs[nt] * g4.z + be4.z);
        s.w = f2bf((y1[cti][nt][3] - mu[nt]) * rs[nt] * g4.w + be4.w);
        *(short4*)(&SP[(wh * 32 + nt * 16 + l15) * 200 + cb + cti * 16 + quad * 4]) = s;
      }
    }
    __syncthreads();               // y1n ready

    // ---- G2: y2 = W1 . y1n^T ----
    v4f y2[3][2];
#pragma unroll
    for (int cti = 0; cti < 3; cti++)
#pragma unroll
      for (int nt = 0; nt < 2; nt++) y2[cti][nt] = vzero;
#pragma unroll
    for (int ks = 0; ks < 6; ks++) {
      v8s bh[2];
#pragma unroll
      for (int nt = 0; nt < 2; nt++)
        bh[nt] = *(const v8s*)(SP + (wh * 32 + nt * 16 + l15) * 200 + ks * 32 + quad * 8);
#pragma unroll
      for (int cti = 0; cti < 3; cti++) {
        v8s a = *(const v8s*)(W1_bf + (size_t)(cb + cti * 16 + l15) * 192 + ks * 32 + quad * 8);
#pragma unroll
        for (int nt = 0; nt < 2; nt++)
          y2[cti][nt] = __builtin_amdgcn_mfma_f32_16x16x32_bf16(a, bh[nt], y2[cti][nt], 0, 0, 0);
      }
    }
    __syncthreads();               // G2 strip reads done before h overwrite
#pragma unroll
    for (int cti = 0; cti < 3; cti++) {
      float4 b14 = *(const float4*)(b1 + cb + cti * 16 + quad * 4);
#pragma unroll
      for (int nt = 0; nt < 2; nt++) {
        float vv[4] = {y2[cti][nt][0] + b14.x, y2[cti][nt][1] + b14.y,
                       y2[cti][nt][2] + b14.z, y2[cti][nt][3] + b14.w};
        short sv[4];
#pragma unroll
        for (int r = 0; r < 4; r++) {
          float v = vv[r];
          float t = 0.79788456080286536f * (v + 0.044715f * v * v * v);
          float e = __expf(2.0f * t);
          float th = 1.0f - 2.0f / (e + 1.0f);
          sv[r] = f2bf(0.5f * v * (1.0f + th));
        }
        short4 s;
        s.x = sv[0]; s.y = sv[1]; s.z = sv[2]; s.w = sv[3];
        *(short4*)(&SP[(wh * 32 + nt * 16 + l15) * 200 + cb + cti * 16 + quad * 4]) = s;
      }
    }
    __syncthreads();               // h ready

    // ---- G3: acc += W2 . h^T ----
#pragma unroll
    for (int ks = 0; ks < 6; ks++) {
      v8s bh[2];
#pragma unroll
      for (int nt = 0; nt < 2; nt++)
        bh[nt] = *(const v8s*)(SP + (wh * 32 + nt * 16 + l15) * 200 + ks * 32 + quad * 8);
#pragma unroll
      for (int cti = 0; cti < 3; cti++) {
        v8s a = *(const v8s*)(W2_bf + (size_t)(cb + cti * 16 + l15) * 192 + ks * 32 + quad * 8);
#pragma unroll
        for (int nt = 0; nt < 2; nt++)
          acc[cti][nt] = __builtin_amdgcn_mfma_f32_16x16x32_bf16(a, bh[nt], acc[cti][nt], 0, 0, 0);
      }
    }
  }

  // ---- epilogue: stage acc/6 to LDS (f32), write full contiguous rows ----
  // SP reused as float staging: 32 rows x pitch 196 f32 = 25088 B <= 25600 B.
  float* SPf = (float*)SP;
#pragma unroll
  for (int pass = 0; pass < 2; pass++) {
    __syncthreads();               // SP (h) reads done / previous pass copy done
    if (wh == pass) {
#pragma unroll
      for (int cti = 0; cti < 3; cti++)
#pragma unroll
        for (int nt = 0; nt < 2; nt++) {
          float4 o4;
          o4.x = acc[cti][nt][0] * (1.0f / 6.0f);
          o4.y = acc[cti][nt][1] * (1.0f / 6.0f);
          o4.z = acc[cti][nt][2] * (1.0f / 6.0f);
          o4.w = acc[cti][nt][3] * (1.0f / 6.0f);
          *(float4*)(&SPf[(nt * 16 + l15) * 196 + cb + cti * 16 + quad * 4]) = o4;
        }
    }
    __syncthreads();
    // 32 rows x 48 float4; both output halves written from one x read
    for (int c = tid; c < 1536; c += 512) {
      int r32 = c / 48, col4 = (c - r32 * 48) * 4;
      int row = pass * 32 + r32;
      size_t nrow = (size_t)b * 384 + (size_t)i * 64 + row;
      float4 xv = *(const float4*)(x + nrow * DIM + col4);
      float4 b24 = *(const float4*)(b2 + col4);
      float4 av = *(const float4*)(&SPf[r32 * 196 + col4]);
      float4 o4;
      o4.x = xv.x + av.x + b24.x;
      o4.y = xv.y + av.y + b24.y;
      o4.z = xv.z + av.z + b24.z;
      o4.w = xv.w + av.w + b24.w;
      *(float4*)(out + nrow * 384 + col4) = xv;             // x half bit-exact
      *(float4*)(out + nrow * 384 + 192 + col4) = o4;
    }
  }
}

extern "C" void kernel_launch(void* const* d_in, const int* in_sizes, int n_in,
                              void* d_out, int out_size, void* d_ws, size_t ws_size,
                              hipStream_t stream) {
  (void)in_sizes; (void)n_in; (void)out_size; (void)ws_size;
  const float* x     = (const float*)d_in[0];
  const float* Wqkv  = (const float*)d_in[1];
  const float* Wproj = (const float*)d_in[2];
  const float* bproj = (const float*)d_in[3];
  const float* gamma = (const float*)d_in[4];
  const float* beta  = (const float*)d_in[5];
  const float* W1    = (const float*)d_in[6];
  const float* b1    = (const float*)d_in[7];
  const float* W2    = (const float*)d_in[8];
  const float* b2    = (const float*)d_in[9];
  float* out = (float*)d_out;

  // workspace: weights bf16 + pos f32 + Q/K/Vt bf16
  short* Wqkv_bf  = (short*)d_ws;                 // 576*192
  short* Wproj_bf = Wqkv_bf + 110592;             // 192*384
  short* W1_bf    = Wproj_bf + 73728;             // 192*192
  short* W2_bf    = W1_bf + 36864;                // 192*192
  float* pos_f    = (float*)(W2_bf + 36864);      // 64*192 f32
  short* Qb       = (short*)(pos_f + 12288);      // [b][t][hw][ch]
  short* Kb       = Qb + 9437184;                 // [b][t][hw][ch]
  short* Vtb      = Kb + 9437184;                 // [b][t][ch][hw]

  prep_kernel<<<dim3(264), dim3(256), 0, stream>>>(
      Wqkv, Wproj, W1, W2, Wqkv_bf, Wproj_bf, W1_bf, W2_bf, pos_f);
  qkv_kernel<<<dim3(TT * NB), dim3(256), 0, stream>>>(x, pos_f, Wqkv_bf, Qb, Kb, Vtb);
  fused_all<<<dim3(TT * NB), dim3(512), 0, stream>>>(
      x, Qb, Kb, Vtb, Wproj_bf, W1_bf, W2_bf, bproj, gamma, beta, b1, b2, out);
}

// Round 4
// 605.000 us; speedup vs baseline: 1.0536x; 1.0457x over previous
//
#include <hip/hip_runtime.h>
#include <cmath>

#define TT   6
#define NB   128
#define DIM  192
#define SCALE 0.17677669529663687f

typedef __attribute__((ext_vector_type(8))) short v8s;
typedef __attribute__((ext_vector_type(4))) float v4f;

__device__ __forceinline__ short f2bf(float f) {
  union { float f; unsigned u; } v; v.f = f;
  unsigned r = v.u + 0x7fffu + ((v.u >> 16) & 1u);
  return (short)(r >> 16);
}

// ---- fused prep: bf16 weight conversion + sine position table, one launch ----
__global__ void prep_kernel(const float* __restrict__ Wqkv, const float* __restrict__ Wproj,
                            const float* __restrict__ W1, const float* __restrict__ W2,
                            short* __restrict__ dWqkv, short* __restrict__ dWproj,
                            short* __restrict__ dW1, short* __restrict__ dW2,
                            float* __restrict__ pos) {
  int idx = blockIdx.x * 256 + threadIdx.x;
  const float* src = nullptr; short* dst = nullptr; int off = 0;
  if (idx < 27648)      { src = Wqkv;  dst = dWqkv;  off = idx; }
  else if (idx < 46080) { src = Wproj; dst = dWproj; off = idx - 27648; }
  else if (idx < 55296) { src = W1;    dst = dW1;    off = idx - 46080; }
  else if (idx < 64512) { src = W2;    dst = dW2;    off = idx - 55296; }
  else if (idx < 67584) {
    int p0 = (idx - 64512) * 4;
    float4 r;
    float* rp = (float*)&r;
#pragma unroll
    for (int jj = 0; jj < 4; jj++) {
      int p = p0 + jj;
      int row = p / 192, c = p - row * 192;
      int e  = (c < 96) ? (row >> 3) : (row & 7);
      int cc = (c < 96) ? c : c - 96;
      int m = cc >> 1;
      float embed = (float)(e + 1) * (6.283185307179586f / 8.000001f);
      float dt = powf(10000.0f, (float)m * (1.0f / 48.0f));
      float ang = embed / dt;
      rp[jj] = (cc & 1) ? cosf(ang) : sinf(ang);
    }
    *(float4*)(pos + p0) = r;
    return;
  } else return;
  const float* s = src + off * 4;
  short4 r;
  r.x = f2bf(s[0]); r.y = f2bf(s[1]); r.z = f2bf(s[2]); r.w = f2bf(s[3]);
  *(short4*)(dst + off * 4) = r;
}

// ---- QKV pre-kernel: one block per (b,t). Q,K row-major [hw][ch]; V transposed [ch][hw].
// Grid swizzled with the SAME XCD mapping as fused_all.
__global__ __launch_bounds__(256) void qkv_kernel(
    const float* __restrict__ x, const float* __restrict__ pos,
    const short* __restrict__ Wqkv_bf,
    short* __restrict__ Qb, short* __restrict__ Kb, short* __restrict__ Vtb) {
  __shared__ short XP[64 * 200];
  int bid = blockIdx.x;
  int xcd = bid & 7, idx = bid >> 3;   // 96 blocks per XCD
  int bq = idx / TT;
  int b = xcd * 16 + bq, t = idx - bq * TT;
  int tid = threadIdx.x, w = tid >> 6, lane = tid & 63;
  int l15 = lane & 15, quad = lane >> 4;
  const float* xrow = x + (size_t)(b * (TT * 64) + t * 64) * DIM;
  for (int c = tid; c < 64 * 24; c += 256) {
    int row = c / 24, col8 = (c - (c / 24) * 24) * 8;
    const float* xs = xrow + row * DIM + col8;
    const float* pp = pos + row * DIM + col8;
    v8s r8;
#pragma unroll
    for (int jj = 0; jj < 8; jj++) r8[jj] = f2bf(xs[jj] + pp[jj]);
    *(v8s*)(XP + row * 200 + col8) = r8;
  }
  __syncthreads();
  const v4f vzero = {0.f, 0.f, 0.f, 0.f};
  size_t obase = (size_t)(b * TT + t) * 64 * DIM;
#pragma unroll
  for (int cti = 0; cti < 9; cti++) {
    int r0 = w * 144 + cti * 16;
    v4f acc[4] = {vzero, vzero, vzero, vzero};
#pragma unroll
    for (int ks = 0; ks < 6; ks++) {
      v8s a = *(const v8s*)(Wqkv_bf + (size_t)(r0 + l15) * 192 + ks * 32 + quad * 8);
#pragma unroll
      for (int nt = 0; nt < 4; nt++) {
        v8s bb = *(const v8s*)(XP + (nt * 16 + l15) * 200 + ks * 32 + quad * 8);
        acc[nt] = __builtin_amdgcn_mfma_f32_16x16x32_bf16(a, bb, acc[nt], 0, 0, 0);
      }
    }
    int R = r0 + quad * 4;
#pragma unroll
    for (int nt = 0; nt < 4; nt++) {
      int hw = nt * 16 + l15;
      if (R < 192) {
        short4 s;
        s.x = f2bf(acc[nt][0] * SCALE); s.y = f2bf(acc[nt][1] * SCALE);
        s.z = f2bf(acc[nt][2] * SCALE); s.w = f2bf(acc[nt][3] * SCALE);
        *(short4*)(Qb + obase + (size_t)hw * 192 + R) = s;
      } else if (R < 384) {
        short4 s;
        s.x = f2bf(acc[nt][0]); s.y = f2bf(acc[nt][1]);
        s.z = f2bf(acc[nt][2]); s.w = f2bf(acc[nt][3]);
        *(short4*)(Kb + obase + (size_t)hw * 192 + (R - 192)) = s;
      } else {
#pragma unroll
        for (int r = 0; r < 4; r++)
          Vtb[obase + (size_t)(R - 384 + r) * 64 + hw] = f2bf(acc[nt][r]);
      }
    }
  }
}

// ---- main fused kernel: one block per (i,b), 512 threads (8 waves).
// __launch_bounds__(512,4): 128-reg cap. The (512,6) variant spilled to scratch
// (VGPR_Count 40, +240MB WRITE / +170MB FETCH of spill traffic) and was SLOWER
// despite 68% occupancy. 2 blocks/CU reg-limited, no spills.
__global__ __launch_bounds__(512, 4) void fused_all(
    const float* __restrict__ x,
    const short* __restrict__ Qb, const short* __restrict__ Kb,
    const short* __restrict__ Vtb,
    const short* __restrict__ Wproj_bf, const short* __restrict__ W1_bf,
    const short* __restrict__ W2_bf,
    const float* __restrict__ bproj, const float* __restrict__ gamma,
    const float* __restrict__ beta, const float* __restrict__ b1,
    const float* __restrict__ b2,
    float* __restrict__ out) {
  __shared__ short SP[64 * 200];     // o / y1n / h: [hw][ch]; f32 acc staging in epilogue
  __shared__ short XI[64 * 200];     // bf16 x-view rows, resident all j
  __shared__ float LNp[64][4][2];    // LN partials: [hw][wc][s1,s2]

  // XCD swizzle: 6 i-blocks sharing b land on one XCD (shared Q/K/V in its L2)
  int bid = blockIdx.x;
  int xcd = bid & 7, idx6 = bid >> 3;
  int bq = idx6 / TT;
  int b = xcd * 16 + bq, i = idx6 - bq * TT;

  int tid = threadIdx.x, w = tid >> 6, lane = tid & 63;
  int l15 = lane & 15, quad = lane >> 4;
  int wc = w & 3, wh = w >> 2;
  int cb = wc * 48;
  const v4f vzero = {0.f, 0.f, 0.f, 0.f};

  // ---- stage Xi (x.view reinterpretation rows) as bf16, resident ----
  const float* xi = x + (size_t)(i * NB + b) * 64 * DIM;
  for (int c = tid; c < 64 * 24; c += 512) {
    int row = c / 24, col8 = (c - (c / 24) * 24) * 8;
    const float* xs = xi + row * DIM + col8;
    v8s r8;
#pragma unroll
    for (int jj = 0; jj < 8; jj++) r8[jj] = f2bf(xs[jj]);
    *(v8s*)(XI + row * 200 + col8) = r8;
  }

  // ---- hoist Q fragments (j-invariant): wave's 16 q-rows x its 3 heads ----
  const short* Qi = Qb + (size_t)(b * TT + i) * 64 * DIM;
  v8s qa[3];
#pragma unroll
  for (int hh = 0; hh < 3; hh++)
    qa[hh] = *(const v8s*)(Qi + (size_t)(wc * 16 + l15) * 192 + (wh * 3 + hh) * 32 + quad * 8);

  v4f acc[3][2];
#pragma unroll
  for (int cti = 0; cti < 3; cti++)
#pragma unroll
    for (int nt = 0; nt < 2; nt++) acc[cti][nt] = vzero;

  __syncthreads();                   // XI staged

  int srcA = l15 + ((lane & 16) << 1);   // l15 + 32*(quad&1)
  int srcB = srcA + 16;
  bool hiq = (lane & 32) != 0;           // quad >= 2

  for (int j = 0; j < TT; j++) {
    __syncthreads();               // prior SP reads (G3 h) done before o overwrites
    const short* Kj = Kb + (size_t)(b * TT + j) * 64 * DIM;
    const short* Vj = Vtb + (size_t)(b * TT + j) * 64 * DIM;

    // ---- attention ----
#pragma unroll
    for (int hh = 0; hh < 3; hh++) {
      int h = wh * 3 + hh;
      v4f S[4];
#pragma unroll
      for (int cta = 0; cta < 4; cta++) {
        v8s akq = *(const v8s*)(Kj + (size_t)(cta * 16 + l15) * 192 + h * 32 + quad * 8);
        S[cta] = __builtin_amdgcn_mfma_f32_16x16x32_bf16(akq, qa[hh], vzero, 0, 0, 0);
      }
      // softmax over k (per lane: q=l15, k=cta*16+quad*4+r)
      float mx = -1e30f;
#pragma unroll
      for (int cta = 0; cta < 4; cta++)
#pragma unroll
        for (int r = 0; r < 4; r++) mx = fmaxf(mx, S[cta][r]);
      mx = fmaxf(mx, __shfl_xor(mx, 16, 64));
      mx = fmaxf(mx, __shfl_xor(mx, 32, 64));
      float sum = 0.f;
#pragma unroll
      for (int cta = 0; cta < 4; cta++)
#pragma unroll
        for (int r = 0; r < 4; r++) {
          float e = __expf(S[cta][r] - mx);
          S[cta][r] = e; sum += e;
        }
      sum += __shfl_xor(sum, 16, 64);
      sum += __shfl_xor(sum, 32, 64);
      float inv = 1.0f / sum;
      // pack P to bf16 pairs -- named scalars (array-element asm outputs can
      // force stack slots under register pressure)
      unsigned pk00, pk01, pk10, pk11, pk20, pk21, pk30, pk31;
      {
        float a0 = S[0][0] * inv, a1 = S[0][1] * inv, a2 = S[0][2] * inv, a3 = S[0][3] * inv;
        __asm__("v_cvt_pk_bf16_f32 %0, %1, %2" : "=v"(pk00) : "v"(a0), "v"(a1));
        __asm__("v_cvt_pk_bf16_f32 %0, %1, %2" : "=v"(pk01) : "v"(a2), "v"(a3));
        float b0 = S[1][0] * inv, b1_ = S[1][1] * inv, b2_ = S[1][2] * inv, b3 = S[1][3] * inv;
        __asm__("v_cvt_pk_bf16_f32 %0, %1, %2" : "=v"(pk10) : "v"(b0), "v"(b1_));
        __asm__("v_cvt_pk_bf16_f32 %0, %1, %2" : "=v"(pk11) : "v"(b2_), "v"(b3));
        float c0 = S[2][0] * inv, c1 = S[2][1] * inv, c2 = S[2][2] * inv, c3 = S[2][3] * inv;
        __asm__("v_cvt_pk_bf16_f32 %0, %1, %2" : "=v"(pk20) : "v"(c0), "v"(c1));
        __asm__("v_cvt_pk_bf16_f32 %0, %1, %2" : "=v"(pk21) : "v"(c2), "v"(c3));
        float d0 = S[3][0] * inv, d1 = S[3][1] * inv, d2 = S[3][2] * inv, d3 = S[3][3] * inv;
        __asm__("v_cvt_pk_bf16_f32 %0, %1, %2" : "=v"(pk30) : "v"(d0), "v"(d1));
        __asm__("v_cvt_pk_bf16_f32 %0, %1, %2" : "=v"(pk31) : "v"(d2), "v"(d3));
      }
      // quad-transpose to PV B-fragment layout; interleave shfl+select to
      // keep peak live temps low
      union { unsigned u[4]; v8s v; } B0, B1;
      {
        unsigned ta = (unsigned)__shfl((int)pk00, srcA), tb = (unsigned)__shfl((int)pk10, srcA);
        B0.u[0] = hiq ? tb : ta;
        ta = (unsigned)__shfl((int)pk01, srcA); tb = (unsigned)__shfl((int)pk11, srcA);
        B0.u[1] = hiq ? tb : ta;
        ta = (unsigned)__shfl((int)pk00, srcB); tb = (unsigned)__shfl((int)pk10, srcB);
        B0.u[2] = hiq ? tb : ta;
        ta = (unsigned)__shfl((int)pk01, srcB); tb = (unsigned)__shfl((int)pk11, srcB);
        B0.u[3] = hiq ? tb : ta;
        ta = (unsigned)__shfl((int)pk20, srcA); tb = (unsigned)__shfl((int)pk30, srcA);
        B1.u[0] = hiq ? tb : ta;
        ta = (unsigned)__shfl((int)pk21, srcA); tb = (unsigned)__shfl((int)pk31, srcA);
        B1.u[1] = hiq ? tb : ta;
        ta = (unsigned)__shfl((int)pk20, srcB); tb = (unsigned)__shfl((int)pk30, srcB);
        B1.u[2] = hiq ? tb : ta;
        ta = (unsigned)__shfl((int)pk21, srcB); tb = (unsigned)__shfl((int)pk31, srcB);
        B1.u[3] = hiq ? tb : ta;
      }
      // PV
#pragma unroll
      for (int ct2 = 0; ct2 < 2; ct2++) {
        v8s av0 = *(const v8s*)(Vj + (size_t)(h * 32 + ct2 * 16 + l15) * 64 + quad * 8);
        v8s av1 = *(const v8s*)(Vj + (size_t)(h * 32 + ct2 * 16 + l15) * 64 + 32 + quad * 8);
        v4f o = __builtin_amdgcn_mfma_f32_16x16x32_bf16(av0, B0.v, vzero, 0, 0, 0);
        o = __builtin_amdgcn_mfma_f32_16x16x32_bf16(av1, B1.v, o, 0, 0, 0);
        short4 s;
        s.x = f2bf(o[0]); s.y = f2bf(o[1]); s.z = f2bf(o[2]); s.w = f2bf(o[3]);
        *(short4*)(&SP[(wc * 16 + l15) * 200 + h * 32 + ct2 * 16 + quad * 4]) = s;
      }
    }
    __syncthreads();               // o complete

    // ---- G1: y1 = Wproj[:,0:192] . o^T + Wproj[:,192:384] . Xi^T ----
    v4f y1[3][2];
#pragma unroll
    for (int cti = 0; cti < 3; cti++)
#pragma unroll
      for (int nt = 0; nt < 2; nt++) y1[cti][nt] = vzero;
#pragma unroll
    for (int ks = 0; ks < 6; ks++) {
      v8s bo[2];
#pragma unroll
      for (int nt = 0; nt < 2; nt++)
        bo[nt] = *(const v8s*)(SP + (wh * 32 + nt * 16 + l15) * 200 + ks * 32 + quad * 8);
#pragma unroll
      for (int cti = 0; cti < 3; cti++) {
        v8s a = *(const v8s*)(Wproj_bf + (size_t)(cb + cti * 16 + l15) * 384 + ks * 32 + quad * 8);
#pragma unroll
        for (int nt = 0; nt < 2; nt++)
          y1[cti][nt] = __builtin_amdgcn_mfma_f32_16x16x32_bf16(a, bo[nt], y1[cti][nt], 0, 0, 0);
      }
    }
#pragma unroll
    for (int ks = 0; ks < 6; ks++) {
      v8s bxi[2];
#pragma unroll
      for (int nt = 0; nt < 2; nt++)
        bxi[nt] = *(const v8s*)(XI + (wh * 32 + nt * 16 + l15) * 200 + ks * 32 + quad * 8);
#pragma unroll
      for (int cti = 0; cti < 3; cti++) {
        v8s a = *(const v8s*)(Wproj_bf + (size_t)(cb + cti * 16 + l15) * 384 + 192 + ks * 32 + quad * 8);
#pragma unroll
        for (int nt = 0; nt < 2; nt++)
          y1[cti][nt] = __builtin_amdgcn_mfma_f32_16x16x32_bf16(a, bxi[nt], y1[cti][nt], 0, 0, 0);
      }
    }
    // + bproj; LN partials
#pragma unroll
    for (int cti = 0; cti < 3; cti++) {
      float4 bp4 = *(const float4*)(bproj + cb + cti * 16 + quad * 4);
#pragma unroll
      for (int nt = 0; nt < 2; nt++) {
        y1[cti][nt][0] += bp4.x; y1[cti][nt][1] += bp4.y;
        y1[cti][nt][2] += bp4.z; y1[cti][nt][3] += bp4.w;
      }
    }
#pragma unroll
    for (int nt = 0; nt < 2; nt++) {
      float s1 = 0.f, s2 = 0.f;
#pragma unroll
      for (int cti = 0; cti < 3; cti++)
#pragma unroll
        for (int r = 0; r < 4; r++) { float v = y1[cti][nt][r]; s1 += v; s2 += v * v; }
      s1 += __shfl_xor(s1, 16, 64); s2 += __shfl_xor(s2, 16, 64);
      s1 += __shfl_xor(s1, 32, 64); s2 += __shfl_xor(s2, 32, 64);
      if (quad == 0) {
        LNp[wh * 32 + nt * 16 + l15][wc][0] = s1;
        LNp[wh * 32 + nt * 16 + l15][wc][1] = s2;
      }
    }
    __syncthreads();               // partials visible; G1 strip reads done
    float mu[2], rs[2];
#pragma unroll
    for (int nt = 0; nt < 2; nt++) {
      int row = wh * 32 + nt * 16 + l15;
      float s1 = 0.f, s2 = 0.f;
#pragma unroll
      for (int ww = 0; ww < 4; ww++) { s1 += LNp[row][ww][0]; s2 += LNp[row][ww][1]; }
      float m = s1 * (1.0f / 192.0f);
      mu[nt] = m; rs[nt] = rsqrtf(s2 * (1.0f / 192.0f) - m * m + 1e-5f);
    }
#pragma unroll
    for (int cti = 0; cti < 3; cti++) {
      float4 g4 = *(const float4*)(gamma + cb + cti * 16 + quad * 4);
      float4 be4 = *(const float4*)(beta + cb + cti * 16 + quad * 4);
#pragma unroll
      for (int nt = 0; nt < 2; nt++) {
        short4 s;
        s.x = f2bf((y1[cti][nt][0] - mu[nt]) * rs[nt] * g4.x + be4.x);
        s.y = f2bf((y1[cti][nt][1] - mu[nt]) * rs[nt] * g4.y + be4.y);
        s.z = f2bf((y1[cti][nt][2] - mu[nt]) * rs[nt] * g4.z + be4.z);
        s.w = f2bf((y1[cti][nt][3] - mu[nt]) * rs[nt] * g4.w + be4.w);
        *(short4*)(&SP[(wh * 32 + nt * 16 + l15) * 200 + cb + cti * 16 + quad * 4]) = s;
      }
    }
    __syncthreads();               // y1n ready

    // ---- G2: y2 = W1 . y1n^T ----
    v4f y2[3][2];
#pragma unroll
    for (int cti = 0; cti < 3; cti++)
#pragma unroll
      for (int nt = 0; nt < 2; nt++) y2[cti][nt] = vzero;
#pragma unroll
    for (int ks = 0; ks < 6; ks++) {
      v8s bh[2];
#pragma unroll
      for (int nt = 0; nt < 2; nt++)
        bh[nt] = *(const v8s*)(SP + (wh * 32 + nt * 16 + l15) * 200 + ks * 32 + quad * 8);
#pragma unroll
      for (int cti = 0; cti < 3; cti++) {
        v8s a = *(const v8s*)(W1_bf + (size_t)(cb + cti * 16 + l15) * 192 + ks * 32 + quad * 8);
#pragma unroll
        for (int nt = 0; nt < 2; nt++)
          y2[cti][nt] = __builtin_amdgcn_mfma_f32_16x16x32_bf16(a, bh[nt], y2[cti][nt], 0, 0, 0);
      }
    }
    __syncthreads();               // G2 strip reads done before h overwrite
#pragma unroll
    for (int cti = 0; cti < 3; cti++) {
      float4 b14 = *(const float4*)(b1 + cb + cti * 16 + quad * 4);
#pragma unroll
      for (int nt = 0; nt < 2; nt++) {
        float vv[4] = {y2[cti][nt][0] + b14.x, y2[cti][nt][1] + b14.y,
                       y2[cti][nt][2] + b14.z, y2[cti][nt][3] + b14.w};
        short sv[4];
#pragma unroll
        for (int r = 0; r < 4; r++) {
          float v = vv[r];
          float t = 0.79788456080286536f * (v + 0.044715f * v * v * v);
          float e = __expf(2.0f * t);
          float th = 1.0f - 2.0f / (e + 1.0f);
          sv[r] = f2bf(0.5f * v * (1.0f + th));
        }
        short4 s;
        s.x = sv[0]; s.y = sv[1]; s.z = sv[2]; s.w = sv[3];
        *(short4*)(&SP[(wh * 32 + nt * 16 + l15) * 200 + cb + cti * 16 + quad * 4]) = s;
      }
    }
    __syncthreads();               // h ready

    // ---- G3: acc += W2 . h^T ----
#pragma unroll
    for (int ks = 0; ks < 6; ks++) {
      v8s bh[2];
#pragma unroll
      for (int nt = 0; nt < 2; nt++)
        bh[nt] = *(const v8s*)(SP + (wh * 32 + nt * 16 + l15) * 200 + ks * 32 + quad * 8);
#pragma unroll
      for (int cti = 0; cti < 3; cti++) {
        v8s a = *(const v8s*)(W2_bf + (size_t)(cb + cti * 16 + l15) * 192 + ks * 32 + quad * 8);
#pragma unroll
        for (int nt = 0; nt < 2; nt++)
          acc[cti][nt] = __builtin_amdgcn_mfma_f32_16x16x32_bf16(a, bh[nt], acc[cti][nt], 0, 0, 0);
      }
    }
  }

  // ---- epilogue: stage acc/6 to LDS (f32), write full contiguous rows ----
  float* SPf = (float*)SP;
#pragma unroll
  for (int pass = 0; pass < 2; pass++) {
    __syncthreads();               // SP (h) reads done / previous pass copy done
    if (wh == pass) {
#pragma unroll
      for (int cti = 0; cti < 3; cti++)
#pragma unroll
        for (int nt = 0; nt < 2; nt++) {
          float4 o4;
          o4.x = acc[cti][nt][0] * (1.0f / 6.0f);
          o4.y = acc[cti][nt][1] * (1.0f / 6.0f);
          o4.z = acc[cti][nt][2] * (1.0f / 6.0f);
          o4.w = acc[cti][nt][3] * (1.0f / 6.0f);
          *(float4*)(&SPf[(nt * 16 + l15) * 196 + cb + cti * 16 + quad * 4]) = o4;
        }
    }
    __syncthreads();
    // 32 rows x 48 float4; both output halves written from one x read
    for (int c = tid; c < 1536; c += 512) {
      int r32 = c / 48, col4 = (c - r32 * 48) * 4;
      int row = pass * 32 + r32;
      size_t nrow = (size_t)b * 384 + (size_t)i * 64 + row;
      float4 xv = *(const float4*)(x + nrow * DIM + col4);
      float4 b24 = *(const float4*)(b2 + col4);
      float4 av = *(const float4*)(&SPf[r32 * 196 + col4]);
      float4 o4;
      o4.x = xv.x + av.x + b24.x;
      o4.y = xv.y + av.y + b24.y;
      o4.z = xv.z + av.z + b24.z;
      o4.w = xv.w + av.w + b24.w;
      *(float4*)(out + nrow * 384 + col4) = xv;             // x half bit-exact
      *(float4*)(out + nrow * 384 + 192 + col4) = o4;
    }
  }
}

extern "C" void kernel_launch(void* const* d_in, const int* in_sizes, int n_in,
                              void* d_out, int out_size, void* d_ws, size_t ws_size,
                              hipStream_t stream) {
  (void)in_sizes; (void)n_in; (void)out_size; (void)ws_size;
  const float* x     = (const float*)d_in[0];
  const float* Wqkv  = (const float*)d_in[1];
  const float* Wproj = (const float*)d_in[2];
  const float* bproj = (const float*)d_in[3];
  const float* gamma = (const float*)d_in[4];
  const float* beta  = (const float*)d_in[5];
  const float* W1    = (const float*)d_in[6];
  const float* b1    = (const float*)d_in[7];
  const float* W2    = (const float*)d_in[8];
  const float* b2    = (const float*)d_in[9];
  float* out = (float*)d_out;

  // workspace: weights bf16 + pos f32 + Q/K/Vt bf16
  short* Wqkv_bf  = (short*)d_ws;                 // 576*192
  short* Wproj_bf = Wqkv_bf + 110592;             // 192*384
  short* W1_bf    = Wproj_bf + 73728;             // 192*192
  short* W2_bf    = W1_bf + 36864;                // 192*192
  float* pos_f    = (float*)(W2_bf + 36864);      // 64*192 f32
  short* Qb       = (short*)(pos_f + 12288);      // [b][t][hw][ch]
  short* Kb       = Qb + 9437184;                 // [b][t][hw][ch]
  short* Vtb      = Kb + 9437184;                 // [b][t][ch][hw]

  prep_kernel<<<dim3(264), dim3(256), 0, stream>>>(
      Wqkv, Wproj, W1, W2, Wqkv_bf, Wproj_bf, W1_bf, W2_bf, pos_f);
  qkv_kernel<<<dim3(TT * NB), dim3(256), 0, stream>>>(x, pos_f, Wqkv_bf, Qb, Kb, Vtb);
  fused_all<<<dim3(TT * NB), dim3(512), 0, stream>>>(
      x, Qb, Kb, Vtb, Wproj_bf, W1_bf, W2_bf, bproj, gamma, beta, b1, b2, out);
}